// Round 1
// baseline (4247.604 us; speedup 1.0000x reference)
//
#include <hip/hip_runtime.h>
#include <math.h>

#define B_ 4
#define T_ 2048
#define C_ 1024
#define D_ 64
#define N_ 16384
#define K_ 32
#define SCALE 0.03125f   // 1/sqrt(1024)

// ---------------------------------------------------------------------------
// QKV projection: q/k/v[b,t,:] = x[b,t,:] @ W + b.  8 rows per block, 192 thr
// (3 groups of 64: q,k,v).  W column reads are 64-lane coalesced; x row in LDS.
// ---------------------------------------------------------------------------
__global__ __launch_bounds__(192) void qkv_proj_kernel(
    const float* __restrict__ x,
    const float* __restrict__ Wq, const float* __restrict__ bq,
    const float* __restrict__ Wk, const float* __restrict__ bk,
    const float* __restrict__ Wv, const float* __restrict__ bvp,
    float* __restrict__ q, float* __restrict__ k, float* __restrict__ v)
{
    __shared__ float xs[8][C_];
    const int tid = threadIdx.x;
    const int row0 = blockIdx.x * 8;
    const float* xr = x + (size_t)row0 * C_;
    for (int i = tid; i < 8 * C_ / 4; i += 192)
        ((float4*)&xs[0][0])[i] = ((const float4*)xr)[i];
    __syncthreads();
    const int g = tid >> 6;
    const int d = tid & 63;
    const float* W    = (g == 0) ? Wq : (g == 1) ? Wk : Wv;
    const float* bias = (g == 0) ? bq : (g == 1) ? bk : bvp;
    float*       o    = (g == 0) ? q  : (g == 1) ? k  : v;
    float acc[8];
    const float b0 = bias[d];
    #pragma unroll
    for (int r = 0; r < 8; ++r) acc[r] = b0;
    #pragma unroll 4
    for (int c = 0; c < C_; ++c) {
        const float wv = W[c * D_ + d];
        #pragma unroll
        for (int r = 0; r < 8; ++r) acc[r] += xs[r][c] * wv;
    }
    #pragma unroll
    for (int r = 0; r < 8; ++r)
        o[(size_t)(row0 + r) * D_ + d] = acc[r];
}

// ---------------------------------------------------------------------------
// Causal attention, one block per (b,t).  Scores row in LDS, two-pass softmax,
// PV with 4 groups of 64 lanes (d = lane -> coalesced v reads).
// ---------------------------------------------------------------------------
__global__ __launch_bounds__(256) void causal_attn_kernel(
    const float* __restrict__ q, const float* __restrict__ k,
    const float* __restrict__ v, float* __restrict__ outc)
{
    __shared__ float qs[D_];
    __shared__ float sc[T_];
    __shared__ float red[4][D_];
    __shared__ float redw[4];
    const int tid = threadIdx.x;
    const int b = blockIdx.x >> 11;
    const int t = blockIdx.x & (T_ - 1);
    if (tid < 64) qs[tid] = q[((size_t)b * T_ + t) * D_ + tid];
    __syncthreads();
    const int nS = t + 1;
    const float* kb = k + (size_t)b * T_ * D_;
    for (int s = tid; s < nS; s += 256) {
        const float* kr = kb + (size_t)s * D_;
        float dot = 0.f;
        #pragma unroll
        for (int d = 0; d < D_; d += 4) {
            const float4 k4 = *(const float4*)(kr + d);
            dot += qs[d]*k4.x + qs[d+1]*k4.y + qs[d+2]*k4.z + qs[d+3]*k4.w;
        }
        sc[s] = dot * SCALE;
    }
    __syncthreads();
    // row max
    float lm = -3.0e38f;
    for (int s = tid; s < nS; s += 256) lm = fmaxf(lm, sc[s]);
    #pragma unroll
    for (int off = 32; off; off >>= 1) lm = fmaxf(lm, __shfl_xor(lm, off));
    if ((tid & 63) == 0) redw[tid >> 6] = lm;
    __syncthreads();
    const float m = fmaxf(fmaxf(redw[0], redw[1]), fmaxf(redw[2], redw[3]));
    __syncthreads();           // everyone has read redw before it is reused
    // exp + sum
    float ls = 0.f;
    for (int s = tid; s < nS; s += 256) {
        const float w = __expf(sc[s] - m);
        sc[s] = w;
        ls += w;
    }
    #pragma unroll
    for (int off = 32; off; off >>= 1) ls += __shfl_xor(ls, off);
    if ((tid & 63) == 0) redw[tid >> 6] = ls;
    __syncthreads();
    const float l = redw[0] + redw[1] + redw[2] + redw[3];
    // PV
    const int g = tid >> 6, d = tid & 63;
    const float* vb = v + (size_t)b * T_ * D_;
    float acc = 0.f;
    for (int s = g; s < nS; s += 4) acc += sc[s] * vb[(size_t)s * D_ + d];
    red[g][d] = acc;
    __syncthreads();
    if (g == 0)
        outc[((size_t)b * T_ + t) * D_ + d] =
            (red[0][d] + red[1][d] + red[2][d] + red[3][d]) / l;
}

// ---------------------------------------------------------------------------
// kNN memory attention, one block per (b,t).  Scores computed in two halves of
// 8192 (32 KB LDS -> 4 blocks/CU); top-32 per half by iterative max-extract,
// then rank-merge 64 -> 32.  Tie-break: lower index (matches jax top_k).
// ---------------------------------------------------------------------------
__global__ __launch_bounds__(256) void knn_attn_kernel(
    const float* __restrict__ q, const float* __restrict__ mem_keys,
    const float* __restrict__ mem_vals, const float* __restrict__ outc,
    const float* __restrict__ gate, float* __restrict__ outp)
{
    __shared__ float sc[N_ / 2];
    __shared__ float rv[4];
    __shared__ int   ri[4];
    __shared__ float topv[64];
    __shared__ int   topi[64];
    __shared__ float wsel[K_];
    __shared__ int   isel[K_];
    __shared__ float msh, lsh;
    const int tid = threadIdx.x;
    const int b = blockIdx.x >> 11;
    const int t = blockIdx.x & (T_ - 1);
    const float* qr = q + ((size_t)b * T_ + t) * D_;
    float qreg[D_];
    #pragma unroll
    for (int d = 0; d < D_; d += 4) {
        const float4 q4 = *(const float4*)(qr + d);
        qreg[d] = q4.x; qreg[d+1] = q4.y; qreg[d+2] = q4.z; qreg[d+3] = q4.w;
    }
    const float* kb = mem_keys + (size_t)b * N_ * D_;
    for (int half = 0; half < 2; ++half) {
        const int base = half * (N_ / 2);
        for (int n = tid; n < N_ / 2; n += 256) {
            const float* kr = kb + (size_t)(base + n) * D_;
            float dot = 0.f;
            #pragma unroll
            for (int d = 0; d < D_; d += 4) {
                const float4 k4 = *(const float4*)(kr + d);
                dot += qreg[d]*k4.x + qreg[d+1]*k4.y + qreg[d+2]*k4.z + qreg[d+3]*k4.w;
            }
            sc[n] = dot;
        }
        __syncthreads();
        for (int kk = 0; kk < K_; ++kk) {
            float bestv = -3.0e38f;
            int   besti = 0x7fffffff;
            for (int n = tid; n < N_ / 2; n += 256) {
                const float s = sc[n];
                if (s > bestv) { bestv = s; besti = n; }
            }
            #pragma unroll
            for (int off = 32; off; off >>= 1) {
                const float v2 = __shfl_xor(bestv, off);
                const int   i2 = __shfl_xor(besti, off);
                if (v2 > bestv || (v2 == bestv && i2 < besti)) { bestv = v2; besti = i2; }
            }
            if ((tid & 63) == 0) { rv[tid >> 6] = bestv; ri[tid >> 6] = besti; }
            __syncthreads();
            if (tid == 0) {
                float bb = rv[0]; int bj = ri[0];
                for (int w2 = 1; w2 < 4; ++w2)
                    if (rv[w2] > bb || (rv[w2] == bb && ri[w2] < bj)) { bb = rv[w2]; bj = ri[w2]; }
                topv[half * K_ + kk] = bb;
                topi[half * K_ + kk] = base + bj;
                sc[bj] = -3.0e38f;
            }
            __syncthreads();
        }
    }
    // merge 64 candidates -> top 32 via unique rank
    const float mv = (tid < 64) ? topv[tid] : -3.0e38f;
    const int   mi = (tid < 64) ? topi[tid] : 0x7fffffff;
    int rank = 0;
    for (int j = 0; j < 64; ++j) {
        const float ov = topv[j]; const int oi = topi[j];
        if (ov > mv || (ov == mv && oi < mi)) ++rank;
    }
    if (tid < 64 && rank == 0) msh = mv;
    __syncthreads();
    if (tid < 64 && rank < K_) {
        wsel[rank] = __expf((mv - msh) * SCALE);
        isel[rank] = mi;
    }
    __syncthreads();
    if (tid == 0) {
        float ssum = 0.f;
        for (int i = 0; i < K_; ++i) ssum += wsel[i];
        lsh = ssum;
    }
    __syncthreads();
    if (tid < 64) {
        const float* vb = mem_vals + (size_t)b * N_ * D_;
        float acc = 0.f;
        for (int i = 0; i < K_; ++i)
            acc += wsel[i] * vb[(size_t)isel[i] * D_ + tid];
        const float gv = gate[0];
        const size_t o = ((size_t)b * T_ + t) * D_ + tid;
        outp[o] = outc[o] * gv + (acc / lsh) * (1.f - gv);
    }
}

extern "C" void kernel_launch(void* const* d_in, const int* in_sizes, int n_in,
                              void* d_out, int out_size, void* d_ws, size_t ws_size,
                              hipStream_t stream) {
    const float* x        = (const float*)d_in[0];
    const float* mem_keys = (const float*)d_in[1];
    const float* mem_vals = (const float*)d_in[2];
    const float* Wq       = (const float*)d_in[3];
    const float* bq       = (const float*)d_in[4];
    const float* Wk       = (const float*)d_in[5];
    const float* bk       = (const float*)d_in[6];
    const float* Wv       = (const float*)d_in[7];
    const float* bv       = (const float*)d_in[8];
    const float* gate     = (const float*)d_in[9];
    float* out = (float*)d_out;

    const size_t btd = (size_t)B_ * T_ * D_;   // 524288
    float* q    = (float*)d_ws;
    float* k    = q + btd;
    float* v    = k + btd;
    float* outc = v + btd;

    qkv_proj_kernel<<<B_ * T_ / 8, 192, 0, stream>>>(x, Wq, bq, Wk, bk, Wv, bv, q, k, v);
    causal_attn_kernel<<<B_ * T_, 256, 0, stream>>>(q, k, v, outc);
    knn_attn_kernel<<<B_ * T_, 256, 0, stream>>>(q, mem_keys, mem_vals, outc, gate, out);
}

// Round 2
// 1107.931 us; speedup vs baseline: 3.8338x; 3.8338x over previous
//
#include <hip/hip_runtime.h>
#include <math.h>

#define B_ 4
#define T_ 2048
#define C_ 1024
#define D_ 64
#define N_ 16384
#define K_ 32
#define SCALE 0.03125f   // 1/sqrt(1024)
#define NEGINF -3.402823e38f

// ---------------------------------------------------------------------------
// QKV projection (unchanged from round 0)
// ---------------------------------------------------------------------------
__global__ __launch_bounds__(192) void qkv_proj_kernel(
    const float* __restrict__ x,
    const float* __restrict__ Wq, const float* __restrict__ bq,
    const float* __restrict__ Wk, const float* __restrict__ bk,
    const float* __restrict__ Wv, const float* __restrict__ bvp,
    float* __restrict__ q, float* __restrict__ k, float* __restrict__ v)
{
    __shared__ float xs[8][C_];
    const int tid = threadIdx.x;
    const int row0 = blockIdx.x * 8;
    const float* xr = x + (size_t)row0 * C_;
    for (int i = tid; i < 8 * C_ / 4; i += 192)
        ((float4*)&xs[0][0])[i] = ((const float4*)xr)[i];
    __syncthreads();
    const int g = tid >> 6;
    const int d = tid & 63;
    const float* W    = (g == 0) ? Wq : (g == 1) ? Wk : Wv;
    const float* bias = (g == 0) ? bq : (g == 1) ? bk : bvp;
    float*       o    = (g == 0) ? q  : (g == 1) ? k  : v;
    float acc[8];
    const float b0 = bias[d];
    #pragma unroll
    for (int r = 0; r < 8; ++r) acc[r] = b0;
    #pragma unroll 4
    for (int c = 0; c < C_; ++c) {
        const float wv = W[c * D_ + d];
        #pragma unroll
        for (int r = 0; r < 8; ++r) acc[r] += xs[r][c] * wv;
    }
    #pragma unroll
    for (int r = 0; r < 8; ++r)
        o[(size_t)(row0 + r) * D_ + d] = acc[r];
}

// ---------------------------------------------------------------------------
// Transpose mem_keys [B][N][D] -> kT [B][D][N]  (64x64 tiles via LDS)
// ---------------------------------------------------------------------------
__global__ __launch_bounds__(256) void transpose_keys_kernel(
    const float* __restrict__ keys, float* __restrict__ kT)
{
    __shared__ float tile[64][68];
    const int tid = threadIdx.x;
    const int b  = blockIdx.x >> 8;
    const int n0 = (blockIdx.x & 255) << 6;
    const float4* in4 = (const float4*)(keys + ((size_t)b * N_ + n0) * D_);
    #pragma unroll
    for (int p = 0; p < 4; ++p) {
        const int fi = tid + p * 256;
        const int n = fi >> 4, c4 = fi & 15;
        const float4 v = in4[n * 16 + c4];
        *(float4*)&tile[n][c4 * 4] = v;
    }
    __syncthreads();
    #pragma unroll
    for (int p = 0; p < 4; ++p) {
        const int fi = tid + p * 256;
        const int d = fi >> 4, n4 = fi & 15;
        float4 v;
        v.x = tile[n4 * 4 + 0][d];
        v.y = tile[n4 * 4 + 1][d];
        v.z = tile[n4 * 4 + 2][d];
        v.w = tile[n4 * 4 + 3][d];
        *(float4*)(kT + ((size_t)b * D_ + d) * N_ + n0 + n4 * 4) = v;
    }
}

// ---------------------------------------------------------------------------
// Causal attention (unchanged from round 0)
// ---------------------------------------------------------------------------
__global__ __launch_bounds__(256) void causal_attn_kernel(
    const float* __restrict__ q, const float* __restrict__ k,
    const float* __restrict__ v, float* __restrict__ outc)
{
    __shared__ float qs[D_];
    __shared__ float sc[T_];
    __shared__ float red[4][D_];
    __shared__ float redw[4];
    const int tid = threadIdx.x;
    const int b = blockIdx.x >> 11;
    const int t = blockIdx.x & (T_ - 1);
    if (tid < 64) qs[tid] = q[((size_t)b * T_ + t) * D_ + tid];
    __syncthreads();
    const int nS = t + 1;
    const float* kb = k + (size_t)b * T_ * D_;
    for (int s = tid; s < nS; s += 256) {
        const float* kr = kb + (size_t)s * D_;
        float dot = 0.f;
        #pragma unroll
        for (int d = 0; d < D_; d += 4) {
            const float4 k4 = *(const float4*)(kr + d);
            dot += qs[d]*k4.x + qs[d+1]*k4.y + qs[d+2]*k4.z + qs[d+3]*k4.w;
        }
        sc[s] = dot * SCALE;
    }
    __syncthreads();
    float lm = -3.0e38f;
    for (int s = tid; s < nS; s += 256) lm = fmaxf(lm, sc[s]);
    #pragma unroll
    for (int off = 32; off; off >>= 1) lm = fmaxf(lm, __shfl_xor(lm, off));
    if ((tid & 63) == 0) redw[tid >> 6] = lm;
    __syncthreads();
    const float m = fmaxf(fmaxf(redw[0], redw[1]), fmaxf(redw[2], redw[3]));
    __syncthreads();
    float ls = 0.f;
    for (int s = tid; s < nS; s += 256) {
        const float w = __expf(sc[s] - m);
        sc[s] = w;
        ls += w;
    }
    #pragma unroll
    for (int off = 32; off; off >>= 1) ls += __shfl_xor(ls, off);
    if ((tid & 63) == 0) redw[tid >> 6] = ls;
    __syncthreads();
    const float l = redw[0] + redw[1] + redw[2] + redw[3];
    const int g = tid >> 6, d = tid & 63;
    const float* vb = v + (size_t)b * T_ * D_;
    float acc = 0.f;
    for (int s = g; s < nS; s += 4) acc += sc[s] * vb[(size_t)s * D_ + d];
    red[g][d] = acc;
    __syncthreads();
    if (g == 0)
        outc[((size_t)b * T_ + t) * D_ + d] =
            (red[0][d] + red[1][d] + red[2][d] + red[3][d]) / l;
}

// ---------------------------------------------------------------------------
// kNN memory attention v2.
// One block = 4 waves; each wave owns 2 queries (TQ=8/block -> key traffic /8).
// Keys read from pre-transposed kT[b][d][n] (float4, 64-lane coalesced).
// Scores held in registers (16/lane/query per 1024-key chunk); running sorted
// top-32 in lanes 0..31 with early-stopped wave-max extraction.
// Epilogue: softmax over 32, V gather, gate combine -- fused.
// ---------------------------------------------------------------------------
__global__ __launch_bounds__(256) void knn_topk_kernel(
    const float* __restrict__ qg, const float* __restrict__ kT,
    const float* __restrict__ mem_vals, const float* __restrict__ outc,
    const float* __restrict__ gate, float* __restrict__ outp)
{
    __shared__ float q_lds[4][2][64];
    const int tid = threadIdx.x;
    const int w = tid >> 6, lane = tid & 63;
    const int bid = blockIdx.x;
    // XCD-aware swizzle: dispatch round-robins XCD = bid%8; give batch b to
    // XCDs {2b, 2b+1} so each 4 MB key panel lives in 8 MB of L2.
    const int b  = (bid & 7) >> 1;
    const int qt = ((bid >> 3) << 1) | (bid & 1);   // 0..255
    const int t0 = qt * 8 + w * 2;                   // queries t0, t0+1

    #pragma unroll
    for (int qq = 0; qq < 2; ++qq)
        q_lds[w][qq][lane] = qg[((size_t)(b * T_ + t0 + qq)) * D_ + lane];
    __syncthreads();

    const float4* kT4 = (const float4*)(kT + (size_t)b * D_ * N_);

    float rv[2];  int rid[2];
    rv[0] = rv[1] = NEGINF;
    rid[0] = rid[1] = 0x7fffffff;

    for (int c = 0; c < 16; ++c) {
        // ---- scores for chunk c: lane holds keys c*1024 + g*256 + lane*4 + j
        float s[2][16];
        #pragma unroll
        for (int qq = 0; qq < 2; ++qq)
            #pragma unroll
            for (int j = 0; j < 16; ++j) s[qq][j] = 0.f;

        for (int dt = 0; dt < 8; ++dt) {
            float qv[2][8];
            #pragma unroll
            for (int qq = 0; qq < 2; ++qq)
                #pragma unroll
                for (int dd = 0; dd < 8; ++dd)
                    qv[qq][dd] = q_lds[w][qq][dt * 8 + dd];
            #pragma unroll
            for (int g = 0; g < 4; ++g) {
                #pragma unroll
                for (int dd = 0; dd < 8; ++dd) {
                    const float4 kf =
                        kT4[(size_t)(dt * 8 + dd) * (N_ / 4) + c * 256 + g * 64 + lane];
                    #pragma unroll
                    for (int qq = 0; qq < 2; ++qq) {
                        s[qq][g * 4 + 0] += kf.x * qv[qq][dd];
                        s[qq][g * 4 + 1] += kf.y * qv[qq][dd];
                        s[qq][g * 4 + 2] += kf.z * qv[qq][dd];
                        s[qq][g * 4 + 3] += kf.w * qv[qq][dd];
                    }
                }
            }
        }

        // ---- early-stopped extraction into running top-32
        #pragma unroll
        for (int qq = 0; qq < 2; ++qq) {
            float lmax = NEGINF; int lslot = 0;
            #pragma unroll
            for (int j = 0; j < 16; ++j)
                if (s[qq][j] > lmax) { lmax = s[qq][j]; lslot = j; }
            float t32 = __shfl(rv[qq], 31);
            for (int it = 0; it < 32; ++it) {
                float wm = lmax;
                #pragma unroll
                for (int off = 32; off; off >>= 1)
                    wm = fmaxf(wm, __shfl_xor(wm, off));
                if (wm <= t32) break;
                const unsigned long long bal = __ballot(lmax == wm);
                const int winner = __ffsll((unsigned long long)bal) - 1;
                const int wslot  = __shfl(lslot, winner);
                const int widx   = (c << 10) + ((wslot >> 2) << 8) + (winner << 2) + (wslot & 3);
                // insert (wm, widx) into sorted-descending list in lanes 0..31
                const unsigned long long gb = __ballot((lane < K_) && (rv[qq] > wm));
                const int pos = __popcll(gb);
                const float sv = __shfl_up(rv[qq], 1);
                const int   si = __shfl_up(rid[qq], 1);
                if (lane > pos)       { rv[qq] = sv; rid[qq] = si; }
                else if (lane == pos) { rv[qq] = wm; rid[qq] = widx; }
                t32 = __shfl(rv[qq], 31);
                // winner clears its slot and rebuilds its local max
                if (lane == winner) {
                    float nm = NEGINF; int ns = 0;
                    #pragma unroll
                    for (int j = 0; j < 16; ++j) {
                        const float vj = (j == lslot) ? NEGINF : s[qq][j];
                        s[qq][j] = vj;
                        if (vj > nm) { nm = vj; ns = j; }
                    }
                    lmax = nm; lslot = ns;
                }
            }
        }
        __syncthreads();   // keep waves chunk-aligned for L1/L2 reuse
    }

    // ---- epilogue: softmax over top-32, gather V, gated combine
    const float gv = gate[0];
    const float* vb = mem_vals + (size_t)b * N_ * D_;
    #pragma unroll
    for (int qq = 0; qq < 2; ++qq) {
        const float m = __shfl(rv[qq], 0);
        float wgt = (lane < K_) ? __expf((rv[qq] - m) * SCALE) : 0.f;
        float ssum = wgt;
        #pragma unroll
        for (int off = 32; off; off >>= 1) ssum += __shfl_xor(ssum, off);
        float acc = 0.f;
        for (int i = 0; i < K_; ++i) {
            const float wi = __shfl(wgt, i);
            const int   ii = __shfl(rid[qq], i);
            acc += wi * vb[(size_t)ii * D_ + lane];
        }
        const size_t o = ((size_t)(b * T_ + t0 + qq)) * D_ + lane;
        outp[o] = outc[o] * gv + (acc / ssum) * (1.f - gv);
    }
}

extern "C" void kernel_launch(void* const* d_in, const int* in_sizes, int n_in,
                              void* d_out, int out_size, void* d_ws, size_t ws_size,
                              hipStream_t stream) {
    const float* x        = (const float*)d_in[0];
    const float* mem_keys = (const float*)d_in[1];
    const float* mem_vals = (const float*)d_in[2];
    const float* Wq       = (const float*)d_in[3];
    const float* bq       = (const float*)d_in[4];
    const float* Wk       = (const float*)d_in[5];
    const float* bk       = (const float*)d_in[6];
    const float* Wv       = (const float*)d_in[7];
    const float* bv       = (const float*)d_in[8];
    const float* gate     = (const float*)d_in[9];
    float* out = (float*)d_out;

    const size_t btd = (size_t)B_ * T_ * D_;   // 524288
    float* q    = (float*)d_ws;
    float* k    = q + btd;
    float* v    = k + btd;
    float* outc = v + btd;
    float* kT   = outc + btd;                  // [B][D][N] = 4*64*16384 floats (16 MB)

    qkv_proj_kernel<<<B_ * T_ / 8, 192, 0, stream>>>(x, Wq, bq, Wk, bk, Wv, bv, q, k, v);
    transpose_keys_kernel<<<B_ * (N_ / 64), 256, 0, stream>>>(mem_keys, kT);
    causal_attn_kernel<<<B_ * T_, 256, 0, stream>>>(q, k, v, outc);
    knn_topk_kernel<<<(B_ * T_) / 8, 256, 0, stream>>>(q, kT, mem_vals, outc, gate, out);
}